// Round 1
// baseline (289.823 us; speedup 1.0000x reference)
//
#include <hip/hip_runtime.h>
#include <math.h>

// Problem constants (from reference)
#define BATCH     2
#define NLAB      256          // 64 bifs * 4 stubs
#define VOX       (192*192*192)  // 7,077,888 voxels per batch
#define VVEC      (VOX/4)        // float4 elements per batch-channel
#define TEMP      0.2f

// ---------------------------------------------------------------------------
// Kernel 1: per-batch histogram of (sum of fg, count) over 256 labels.
// fg = softmax(pred, ch)[1] = sigmoid(p1 - p0) since C == 2.
// LDS-privatized per block, flushed with global float atomicAdd.
// Counts kept in float: all values are integers < 2^24, so exact.
// ---------------------------------------------------------------------------
__global__ __launch_bounds__(256) void histo_kernel(
    const float* __restrict__ pred,     // [B,2,V]
    const float* __restrict__ labmap,   // [B,1,V]
    float* __restrict__ ws_sums,        // [B,256]
    float* __restrict__ ws_cnts)        // [B,256]
{
    __shared__ float s_sum[NLAB];
    __shared__ float s_cnt[NLAB];
    const int b = blockIdx.y;

    for (int i = threadIdx.x; i < NLAB; i += blockDim.x) {
        s_sum[i] = 0.0f;
        s_cnt[i] = 0.0f;
    }
    __syncthreads();

    const float4* p0 = (const float4*)(pred + (size_t)b * 2 * VOX);
    const float4* p1 = (const float4*)(pred + (size_t)b * 2 * VOX + VOX);
    const float4* lm = (const float4*)(labmap + (size_t)b * VOX);

    const int stride = gridDim.x * blockDim.x;
    for (int i = blockIdx.x * blockDim.x + threadIdx.x; i < VVEC; i += stride) {
        float4 a = p0[i];   // channel 0
        float4 c = p1[i];   // channel 1
        float4 l = lm[i];   // labels (exact integers 0..255 stored as float)

        float fg0 = 1.0f / (1.0f + __expf(a.x - c.x));
        float fg1 = 1.0f / (1.0f + __expf(a.y - c.y));
        float fg2 = 1.0f / (1.0f + __expf(a.z - c.z));
        float fg3 = 1.0f / (1.0f + __expf(a.w - c.w));

        int l0 = ((int)(l.x + 0.5f)) & (NLAB - 1);
        int l1 = ((int)(l.y + 0.5f)) & (NLAB - 1);
        int l2 = ((int)(l.z + 0.5f)) & (NLAB - 1);
        int l3 = ((int)(l.w + 0.5f)) & (NLAB - 1);

        atomicAdd(&s_sum[l0], fg0);  atomicAdd(&s_cnt[l0], 1.0f);
        atomicAdd(&s_sum[l1], fg1);  atomicAdd(&s_cnt[l1], 1.0f);
        atomicAdd(&s_sum[l2], fg2);  atomicAdd(&s_cnt[l2], 1.0f);
        atomicAdd(&s_sum[l3], fg3);  atomicAdd(&s_cnt[l3], 1.0f);
    }
    __syncthreads();

    for (int i = threadIdx.x; i < NLAB; i += blockDim.x) {
        float sc = s_cnt[i];
        if (sc > 0.0f) {
            atomicAdd(&ws_sums[b * NLAB + i], s_sum[i]);
            atomicAdd(&ws_cnts[b * NLAB + i], sc);
        }
    }
}

// ---------------------------------------------------------------------------
// Kernel 2: 63 bifs x 3 stubs x 2 batches -> masked softmin -> scalar loss.
// One wave (64 threads); thread t handles bif t (bif 0 dropped per reference).
// ---------------------------------------------------------------------------
__global__ __launch_bounds__(64) void finalize_kernel(
    const float* __restrict__ ws_sums,
    const float* __restrict__ ws_cnts,
    float* __restrict__ out)
{
    const int t = threadIdx.x;   // 0..63
    float total = 0.0f;
    float nbifs = 0.0f;

    if (t >= 1) {  // bifs 1..63 (reference drops bif 0)
        for (int b = 0; b < BATCH; ++b) {
            float means[3];
            bool  valid[3];
            int   nvalid = 0;
            for (int s = 0; s < 3; ++s) {
                // stub index s+1 (stub 0 dropped)
                int lab = t * 4 + 1 + s;
                float cnt = ws_cnts[b * NLAB + lab];
                float sum = ws_sums[b * NLAB + lab];
                valid[s] = (cnt >= 1.0f);            // MIN_VOXELS = 1
                means[s] = sum / fmaxf(cnt, 1.0f);
                nvalid  += valid[s] ? 1 : 0;
            }
            // masked softmax of logits = valid ? -mean/TEMP : -1e9
            float logits[3], m = -3e38f;
            for (int s = 0; s < 3; ++s) {
                logits[s] = valid[s] ? (-means[s] / TEMP) : -1e9f;
                m = fmaxf(m, logits[s]);
            }
            float e[3], se = 0.0f;
            for (int s = 0; s < 3; ++s) { e[s] = expf(logits[s] - m); se += e[s]; }
            float score = 0.0f;
            for (int s = 0; s < 3; ++s) {
                if (valid[s]) score += means[s] * (e[s] / se);
            }
            if (nvalid >= 2) {  // MIN_STUBS = 2
                total += 1.0f - score;
                nbifs += 1.0f;
            }
        }
    }

    // reduce across the single 64-lane wave
    for (int off = 32; off > 0; off >>= 1) {
        total += __shfl_down(total, off);
        nbifs += __shfl_down(nbifs, off);
    }
    if (t == 0) {
        out[0] = (nbifs > 0.0f) ? (total / fmaxf(nbifs, 1.0f)) : 0.0f;
    }
}

// ---------------------------------------------------------------------------
extern "C" void kernel_launch(void* const* d_in, const int* in_sizes, int n_in,
                              void* d_out, int out_size, void* d_ws, size_t ws_size,
                              hipStream_t stream) {
    const float* pred = (const float*)d_in[0];   // [B,C,D,H,W] fp32
    const float* lab  = (const float*)d_in[1];   // [B,1,D,H,W] fp32

    float* ws_sums = (float*)d_ws;               // [B,256]
    float* ws_cnts = ws_sums + BATCH * NLAB;     // [B,256]

    // ws is re-poisoned to 0xAA before every call — zero the accumulators.
    hipMemsetAsync(d_ws, 0, (size_t)(2 * BATCH * NLAB) * sizeof(float), stream);

    dim3 grid(512, BATCH);
    histo_kernel<<<grid, 256, 0, stream>>>(pred, lab, ws_sums, ws_cnts);
    finalize_kernel<<<1, 64, 0, stream>>>(ws_sums, ws_cnts, (float*)d_out);
}